// Round 1
// baseline (132771.387 us; speedup 1.0000x reference)
//
#include <hip/hip_runtime.h>

#define T_STEPS 65536
#define IN_DIM 5
#define H1 26
#define H2 121

__device__ __forceinline__ float fsig(float x) {
    // 1/(1+e^-x); exp2-based. x->+inf: rcp(1)=1; x->-inf: rcp(inf)=0. No NaN.
    float e = __builtin_amdgcn_exp2f(-1.44269504f * x);
    return __builtin_amdgcn_rcpf(1.0f + e);
}
__device__ __forceinline__ float ftanh(float x) {
    // tanh = 1 - 2/(1+e^{2x}). x->+inf: 1-2*rcp(inf)=1; x->-inf: 1-2*rcp(1)=-1.
    float e = __builtin_amdgcn_exp2f(2.88539008f * x);
    return 1.0f - 2.0f * __builtin_amdgcn_rcpf(e + 1.0f);
}

// One persistent workgroup. 1024 threads = 16 waves (4/SIMD -> <=128 VGPR).
// threads 0..959       : gates2 rows 0..479, 2 threads/row (half=tid&1)
// wave 15 lanes 0..51  : LSTM1 (rows l, l+52), act by lanes<26 (intra-wave only)
// wave 15 lanes 52..59 : gates2 rows 480..483 (2 threads/row)
// wave 15 lane 60      : y-store of previous step
// threads 0..127       : h2/c2 activation + y butterfly reduce (after B2)
__global__ __launch_bounds__(1024, 4) void lstm_seq_kernel(
    const float* __restrict__ x,
    const float* __restrict__ W_ih1, const float* __restrict__ W_hh1,
    const float* __restrict__ b_ih1, const float* __restrict__ b_hh1,
    const float* __restrict__ W_ih2, const float* __restrict__ W_hh2,
    const float* __restrict__ b_ih2, const float* __restrict__ b_hh2,
    const float* __restrict__ W_lin, const float* __restrict__ b_lin,
    const float* __restrict__ h1_0, const float* __restrict__ c1_0,
    const float* __restrict__ h2_0, const float* __restrict__ c2_0,
    float* __restrict__ out)
{
    __shared__ __align__(16) float h1_lds[32];    // 26 + zero pad
    __shared__ __align__(16) float h2_lds[128];   // 121 + zero pad
    __shared__ float g1_lds[104];
    __shared__ float g2_lds[484];
    __shared__ float ypart[2];

    const int tid = threadIdx.x;
    const int lane15 = tid - 960;                 // valid when tid>=960
    const bool in_w15 = (tid >= 960);
    const bool is_g2 = (tid < 960) || (lane15 >= 52 && lane15 < 60);
    const int row  = (tid < 960) ? (tid >> 1) : (480 + ((tid - 1012) >> 1));
    const int half = tid & 1;

    // ---- overlaid weight register file (union across thread roles) ----
    // gates2 threads: [0..63] = W_hh2 row-half (zero padded past 121)
    //                 [64..79] = W_ih2 row-half (zero padded past 26)
    // LSTM1 threads:  [s*32+k] = W_hh1 rows (k<26, zero pad)
    //                 [64+s*5+i] = W_ih1 rows, [74+s] = bias rows, [76] = c1
    float wreg[80];
    #pragma unroll
    for (int i = 0; i < 80; ++i) wreg[i] = 0.0f;

    float c2 = 0.0f, wlin = 0.0f, accbias = 0.0f;

    if (is_g2) {
        #pragma unroll
        for (int m = 0; m < 64; ++m) {
            int k = half * 64 + m;
            wreg[m] = (k < H2) ? W_hh2[row * H2 + k] : 0.0f;
        }
        #pragma unroll
        for (int m = 0; m < 16; ++m) {
            int k = half * 16 + m;
            wreg[64 + m] = (k < H1) ? W_ih2[row * H1 + k] : 0.0f;
        }
        accbias = (half == 0) ? (b_ih2[row] + b_hh2[row]) : 0.0f;
    } else if (lane15 < 52) {
        #pragma unroll
        for (int s = 0; s < 2; ++s) {
            int r = lane15 + 52 * s;
            #pragma unroll
            for (int k = 0; k < 32; ++k)
                wreg[s * 32 + k] = (k < H1) ? W_hh1[r * H1 + k] : 0.0f;
            #pragma unroll
            for (int i = 0; i < 5; ++i)
                wreg[64 + s * 5 + i] = W_ih1[r * 5 + i];
            wreg[74 + s] = b_ih1[r] + b_hh1[r];
        }
        if (lane15 < H1) wreg[76] = c1_0[lane15];
    }
    if (tid < H2) { c2 = c2_0[tid]; wlin = W_lin[tid]; }

    if (tid < 32)  h1_lds[tid] = (tid < H1) ? h1_0[tid] : 0.0f;
    if (tid < 128) h2_lds[tid] = (tid < H2) ? h2_0[tid] : 0.0f;
    const float blin = b_lin[0];
    __syncthreads();

    const float4* h2v4 = reinterpret_cast<const float4*>(h2_lds);
    const float4* h1v4 = reinterpret_cast<const float4*>(h1_lds);

    float acc = 0.0f;

    for (int t = 0; t < T_STEPS; ++t) {
        // ---------------- Phase A: W_hh2 @ h2(t-1), LSTM1, y-store ----------
        if (is_g2) {
            acc = accbias;
            #pragma unroll
            for (int m4 = 0; m4 < 16; ++m4) {
                float4 h = h2v4[half * 16 + m4];
                acc = fmaf(wreg[4 * m4 + 0], h.x, acc);
                acc = fmaf(wreg[4 * m4 + 1], h.y, acc);
                acc = fmaf(wreg[4 * m4 + 2], h.z, acc);
                acc = fmaf(wreg[4 * m4 + 3], h.w, acc);
            }
        }
        if (in_w15) {
            if (lane15 < 52) {
                const float* xt = x + t * IN_DIM;
                float g0 = wreg[74], g1v = wreg[75];
                #pragma unroll
                for (int i = 0; i < 5; ++i) {
                    float xv = xt[i];
                    g0  = fmaf(wreg[64 + i], xv, g0);
                    g1v = fmaf(wreg[69 + i], xv, g1v);
                }
                #pragma unroll
                for (int q = 0; q < 8; ++q) {
                    float4 h = h1v4[q];
                    g0  = fmaf(wreg[4 * q + 0], h.x, g0);
                    g0  = fmaf(wreg[4 * q + 1], h.y, g0);
                    g0  = fmaf(wreg[4 * q + 2], h.z, g0);
                    g0  = fmaf(wreg[4 * q + 3], h.w, g0);
                    g1v = fmaf(wreg[32 + 4 * q + 0], h.x, g1v);
                    g1v = fmaf(wreg[32 + 4 * q + 1], h.y, g1v);
                    g1v = fmaf(wreg[32 + 4 * q + 2], h.z, g1v);
                    g1v = fmaf(wreg[32 + 4 * q + 3], h.w, g1v);
                }
                g1_lds[lane15]      = g0;
                g1_lds[lane15 + 52] = g1v;
                asm volatile("s_waitcnt lgkmcnt(0)" ::: "memory");
                if (lane15 < H1) {
                    float gi = g1_lds[lane15];
                    float gf = g1_lds[H1 + lane15];
                    float gg = g1_lds[2 * H1 + lane15];
                    float go = g1_lds[3 * H1 + lane15];
                    float c1 = wreg[76];
                    c1 = fsig(gf) * c1 + fsig(gi) * ftanh(gg);
                    wreg[76] = c1;
                    h1_lds[lane15] = fsig(go) * ftanh(c1);
                }
            } else if (lane15 == 60) {
                if (t > 0) out[t - 1] = ypart[0] + ypart[1] + blin;
            }
        }
        __syncthreads();  // B1: h1(t) visible

        // ---------------- Phase C: += W_ih2 @ h1(t), combine halves ---------
        if (is_g2) {
            #pragma unroll
            for (int q = 0; q < 4; ++q) {
                float4 h = h1v4[half * 4 + q];
                acc = fmaf(wreg[64 + 4 * q + 0], h.x, acc);
                acc = fmaf(wreg[64 + 4 * q + 1], h.y, acc);
                acc = fmaf(wreg[64 + 4 * q + 2], h.z, acc);
                acc = fmaf(wreg[64 + 4 * q + 3], h.w, acc);
            }
            acc += __shfl_xor(acc, 1);
            if (half == 0) g2_lds[row] = acc;
        }
        __syncthreads();  // B2: gates2 visible

        // ---------------- Act: c2/h2 update + y partial reduce --------------
        if (tid < 128) {
            float p = 0.0f;
            if (tid < H2) {
                float gi = g2_lds[tid];
                float gf = g2_lds[H2 + tid];
                float gg = g2_lds[2 * H2 + tid];
                float go = g2_lds[3 * H2 + tid];
                c2 = fsig(gf) * c2 + fsig(gi) * ftanh(gg);
                float h2n = fsig(go) * ftanh(c2);
                h2_lds[tid] = h2n;
                p = h2n * wlin;
            }
            #pragma unroll
            for (int off = 32; off >= 1; off >>= 1)
                p += __shfl_xor(p, off);
            if ((tid & 63) == 0) ypart[tid >> 6] = p;
        }
        __syncthreads();  // B3: h2(t), ypart visible
    }

    if (tid == 1020) out[T_STEPS - 1] = ypart[0] + ypart[1] + blin;
}

extern "C" void kernel_launch(void* const* d_in, const int* in_sizes, int n_in,
                              void* d_out, int out_size, void* d_ws, size_t ws_size,
                              hipStream_t stream) {
    const float* x     = (const float*)d_in[0];
    const float* W_ih1 = (const float*)d_in[1];
    const float* W_hh1 = (const float*)d_in[2];
    const float* b_ih1 = (const float*)d_in[3];
    const float* b_hh1 = (const float*)d_in[4];
    const float* W_ih2 = (const float*)d_in[5];
    const float* W_hh2 = (const float*)d_in[6];
    const float* b_ih2 = (const float*)d_in[7];
    const float* b_hh2 = (const float*)d_in[8];
    const float* W_lin = (const float*)d_in[9];
    const float* b_lin = (const float*)d_in[10];
    const float* h1_0  = (const float*)d_in[11];
    const float* c1_0  = (const float*)d_in[12];
    const float* h2_0  = (const float*)d_in[13];
    const float* c2_0  = (const float*)d_in[14];
    float* out = (float*)d_out;

    hipLaunchKernelGGL(lstm_seq_kernel, dim3(1), dim3(1024), 0, stream,
                       x, W_ih1, W_hh1, b_ih1, b_hh1,
                       W_ih2, W_hh2, b_ih2, b_hh2,
                       W_lin, b_lin, h1_0, c1_0, h2_0, c2_0, out);
}